// Round 1
// baseline (195.257 us; speedup 1.0000x reference)
//
#include <hip/hip_runtime.h>

// GauntTensorProductFixedParity: per-row fused SH tensor product.
// LMAX=4 -> S=25 coeffs; grid RB=12 x RA=11 -> P=132 points; D=64; N=131072.
//
// out[n,s] = sum_p ( (c1[n,:]·Y[p,:]) * (c2[n,:]·Y[p,:]) ) * Yw[p,s]
// with c1 = in1 @ W1, c2 = in2 @ W2.
//
// Structure: 1 thread = 1 row. W1/W2/Y/Yw accessed with wave-uniform indices
// (loop counters only) -> scalar s_load path, SGPR operands into v_fmac.
// Inputs via float4 loads. Output staged through LDS for coalesced stores.

namespace {
constexpr int kD = 64;
constexpr int kS = 25;
constexpr int kP = 132;   // RB * RA
constexpr int kBlock = 256;
}

__global__ __launch_bounds__(kBlock, 2) void gaunt_fused(
    const float* __restrict__ in1, const float* __restrict__ in2,
    const float* __restrict__ W1, const float* __restrict__ W2,
    const float* __restrict__ Y,  const float* __restrict__ Yw,
    float* __restrict__ out)
{
    __shared__ float lds_out[kBlock * kS];   // 25.6 KB

    const int tid = threadIdx.x;
    const long long n = (long long)blockIdx.x * kBlock + tid;

    const float4* __restrict__ in1v =
        reinterpret_cast<const float4*>(in1) + n * (kD / 4);
    const float4* __restrict__ in2v =
        reinterpret_cast<const float4*>(in2) + n * (kD / 4);

    // ---- Stage 1: c1 = in1_row @ W1, c2 = in2_row @ W2 ----
    float c1[kS], c2[kS];
    #pragma unroll
    for (int s = 0; s < kS; ++s) { c1[s] = 0.f; c2[s] = 0.f; }

    #pragma unroll
    for (int i = 0; i < kD / 4; ++i) {
        const float4 a = in1v[i];
        const float4 b = in2v[i];
        const float xa[4] = {a.x, a.y, a.z, a.w};
        const float xb[4] = {b.x, b.y, b.z, b.w};
        #pragma unroll
        for (int k = 0; k < 4; ++k) {
            const float* __restrict__ w1r = W1 + (4 * i + k) * kS;
            const float* __restrict__ w2r = W2 + (4 * i + k) * kS;
            #pragma unroll
            for (int s = 0; s < kS; ++s) {
                c1[s] = fmaf(xa[k], w1r[s], c1[s]);
                c2[s] = fmaf(xb[k], w2r[s], c2[s]);
            }
        }
    }

    // ---- Stage 2: grid eval, pointwise product, quadrature projection ----
    float acc[kS];
    #pragma unroll
    for (int s = 0; s < kS; ++s) acc[s] = 0.f;

    #pragma unroll 2
    for (int p = 0; p < kP; ++p) {
        const float* __restrict__ yr  = Y  + p * kS;
        const float* __restrict__ ywr = Yw + p * kS;
        float g1a = 0.f, g1b = 0.f, g2a = 0.f, g2b = 0.f;
        #pragma unroll
        for (int s = 0; s < kS - 1; s += 2) {
            g1a = fmaf(c1[s],     yr[s],     g1a);
            g1b = fmaf(c1[s + 1], yr[s + 1], g1b);
            g2a = fmaf(c2[s],     yr[s],     g2a);
            g2b = fmaf(c2[s + 1], yr[s + 1], g2b);
        }
        g1a = fmaf(c1[kS - 1], yr[kS - 1], g1a);
        g2a = fmaf(c2[kS - 1], yr[kS - 1], g2a);
        const float pr = (g1a + g1b) * (g2a + g2b);
        #pragma unroll
        for (int s = 0; s < kS; ++s) acc[s] = fmaf(pr, ywr[s], acc[s]);
    }

    // ---- Coalesced store via LDS transpose ----
    #pragma unroll
    for (int s = 0; s < kS; ++s) lds_out[tid * kS + s] = acc[s];
    __syncthreads();

    float* __restrict__ oblk = out + (long long)blockIdx.x * kBlock * kS;
    #pragma unroll
    for (int i = 0; i < kS; ++i)
        oblk[i * kBlock + tid] = lds_out[i * kBlock + tid];
}

extern "C" void kernel_launch(void* const* d_in, const int* in_sizes, int n_in,
                              void* d_out, int out_size, void* d_ws, size_t ws_size,
                              hipStream_t stream) {
    const float* in1 = (const float*)d_in[0];   // [N, 64]
    const float* in2 = (const float*)d_in[1];   // [N, 64]
    const float* W1  = (const float*)d_in[2];   // [64, 25]
    const float* W2  = (const float*)d_in[3];   // [64, 25]
    const float* Y   = (const float*)d_in[4];   // [12, 11, 25] -> [132, 25]
    const float* Yw  = (const float*)d_in[5];   // [132, 25]
    float* out = (float*)d_out;                 // [N, 25]

    const int n_rows = in_sizes[0] / kD;        // 131072
    const int grid = n_rows / kBlock;           // 512

    gaunt_fused<<<grid, kBlock, 0, stream>>>(in1, in2, W1, W2, Y, Yw, out);
}

// Round 2
// 176.876 us; speedup vs baseline: 1.1039x; 1.1039x over previous
//
#include <hip/hip_runtime.h>

// GauntTensorProductFixedParity — R2: coalesced LDS staging + wave-uniform slices.
// out[n,s] = sum_p (c1[n]·Y[p]) * (c2[n]·Y[p]) * Yw[p,s],  c_i = in_i @ W_i.
// N=131072, D=64, S=25, P=132.
//
// Block = 256 threads = 4 waves, handles 64 rows. lane (0..63) = row.
// Phase 0: coalesced float4 staging of in1/in2 (64 rows) into LDS.
// Phase 1: wave w computes a 13-wide s-slice of c1 (w=0,1) or c2 (w=2,3);
//          W address is wave-uniform -> s_load. c -> LDS (stride 53, 2-way).
// Phase 2: each lane loads its full c row (50 regs); wave w walks 33 grid
//          points (p wave-uniform -> s_load of Y/Yw rows); acc[25] in regs.
// Phase 3: 4 partial acc sets -> LDS (reusing input region), tree-summed and
//          stored coalesced.

namespace {
constexpr int kD = 64, kS = 25, kBlock = 256, kRows = 64;
constexpr int kInStride = 65;                      // odd pad: 2-way banks only
constexpr int kCStride  = 53;                      // 50 used, odd pad
constexpr int kOffIn1 = 0;
constexpr int kOffIn2 = kRows * kInStride;         // 4160
constexpr int kOffC   = 2 * kRows * kInStride;     // 8320
constexpr int kOffPart = 0;                        // reuse input region (6400 fl)
constexpr int kSmemF = kOffC + kRows * kCStride;   // 11712 floats = 46.8 KB
}

__global__ __launch_bounds__(kBlock, 3) void gaunt_fused2(
    const float* __restrict__ in1, const float* __restrict__ in2,
    const float* __restrict__ W1, const float* __restrict__ W2,
    const float* __restrict__ Y,  const float* __restrict__ Yw,
    float* __restrict__ out)
{
    __shared__ float smem[kSmemF];
    const int tid  = threadIdx.x;
    const int lane = tid & 63;
    const int w    = __builtin_amdgcn_readfirstlane(tid >> 6);  // wave id, SGPR

    // ---- Phase 0: coalesced staging of this block's 64 rows ----
    const long long base = (long long)blockIdx.x * (kRows * kD);
    const float4* __restrict__ g1v = reinterpret_cast<const float4*>(in1 + base);
    const float4* __restrict__ g2v = reinterpret_cast<const float4*>(in2 + base);
    #pragma unroll
    for (int i = 0; i < (kRows * kD) / (4 * kBlock); ++i) {   // 4 iters
        const int idx = i * kBlock + tid;          // float4 index in [0,1024)
        const float4 v1 = g1v[idx];
        const float4 v2 = g2v[idx];
        const int row = idx >> 4;                  // (idx*4)/64
        const int col = (idx & 15) * 4;
        float* d1 = smem + kOffIn1 + row * kInStride + col;
        float* d2 = smem + kOffIn2 + row * kInStride + col;
        d1[0] = v1.x; d1[1] = v1.y; d1[2] = v1.z; d1[3] = v1.w;
        d2[0] = v2.x; d2[1] = v2.y; d2[2] = v2.z; d2[3] = v2.w;
    }
    __syncthreads();

    // ---- Phase 1: c slices. wave 0: c1 s0..12, wave 1: c1 s12..24,
    //      wave 2: c2 s0..12, wave 3: c2 s12..24 (s=12 duplicated, identical).
    {
        const float* __restrict__ Win = (w < 2) ? W1 : W2;      // uniform
        const int s0    = (w & 1) * 12;                          // uniform
        const int cbase = (w < 2) ? 0 : kS;                      // uniform
        const float* irow = smem + ((w < 2) ? kOffIn1 : kOffIn2)
                          + lane * kInStride;
        float cp[13];
        #pragma unroll
        for (int s = 0; s < 13; ++s) cp[s] = 0.f;
        #pragma unroll 8
        for (int k = 0; k < kD; ++k) {
            const float x = irow[k];                 // ds_read_b32, 2-way banks
            const float* __restrict__ wr = Win + k * kS + s0;  // uniform->s_load
            #pragma unroll
            for (int s = 0; s < 13; ++s) cp[s] = fmaf(x, wr[s], cp[s]);
        }
        float* crow = smem + kOffC + lane * kCStride + cbase + s0;
        #pragma unroll
        for (int s = 0; s < 13; ++s) crow[s] = cp[s];
    }
    __syncthreads();

    // ---- Phase 2: 33 grid points per wave, acc in registers ----
    float c1r[kS], c2r[kS], acc[kS];
    {
        const float* crow = smem + kOffC + lane * kCStride;
        #pragma unroll
        for (int s = 0; s < kS; ++s) {
            c1r[s] = crow[s];
            c2r[s] = crow[kS + s];
            acc[s] = 0.f;
        }
    }
    const int p0 = w * 33;                                       // uniform
    #pragma unroll 1
    for (int i = 0; i < 33; ++i) {
        const float* __restrict__ yr  = Y  + (p0 + i) * kS;      // uniform
        const float* __restrict__ ywr = Yw + (p0 + i) * kS;      // uniform
        float g1a = 0.f, g1b = 0.f, g2a = 0.f, g2b = 0.f;
        #pragma unroll
        for (int s = 0; s < kS - 1; s += 2) {
            g1a = fmaf(c1r[s],     yr[s],     g1a);
            g1b = fmaf(c1r[s + 1], yr[s + 1], g1b);
            g2a = fmaf(c2r[s],     yr[s],     g2a);
            g2b = fmaf(c2r[s + 1], yr[s + 1], g2b);
        }
        g1a = fmaf(c1r[kS - 1], yr[kS - 1], g1a);
        g2a = fmaf(c2r[kS - 1], yr[kS - 1], g2a);
        const float pr = (g1a + g1b) * (g2a + g2b);
        #pragma unroll
        for (int s = 0; s < kS; ++s) acc[s] = fmaf(pr, ywr[s], acc[s]);
    }

    // ---- Phase 3: cross-wave reduction via LDS (input region is dead) ----
    {
        float* prt = smem + kOffPart + (w * kRows + lane) * kS;
        #pragma unroll
        for (int s = 0; s < kS; ++s) prt[s] = acc[s];
    }
    __syncthreads();

    {
        const float* po = smem + kOffPart;
        float* __restrict__ ob = out + (long long)blockIdx.x * (kRows * kS);
        #pragma unroll
        for (int e = tid; e < kRows * kS; e += kBlock) {
            const float v = po[e] + po[1600 + e] + po[3200 + e] + po[4800 + e];
            ob[e] = v;                                 // coalesced
        }
    }
}

extern "C" void kernel_launch(void* const* d_in, const int* in_sizes, int n_in,
                              void* d_out, int out_size, void* d_ws, size_t ws_size,
                              hipStream_t stream) {
    const float* in1 = (const float*)d_in[0];   // [N, 64]
    const float* in2 = (const float*)d_in[1];   // [N, 64]
    const float* W1  = (const float*)d_in[2];   // [64, 25]
    const float* W2  = (const float*)d_in[3];   // [64, 25]
    const float* Y   = (const float*)d_in[4];   // [132, 25]
    const float* Yw  = (const float*)d_in[5];   // [132, 25]
    float* out = (float*)d_out;                 // [N, 25]

    const int n_rows = in_sizes[0] / kD;        // 131072
    const int grid = n_rows / kRows;            // 2048

    gaunt_fused2<<<grid, kBlock, 0, stream>>>(in1, in2, W1, W2, Y, Yw, out);
}

// Round 3
// 158.315 us; speedup vs baseline: 1.2333x; 1.1172x over previous
//
#include <hip/hip_runtime.h>
#include <math.h>

// GauntTensorProductFixedParity — R3: separable grid (beta x alpha) + wave-uniform
// scalar loads + 33.3KB LDS for 50% occupancy.
//
// out[n,s] = sum_{b,a} (c1.Y[b,a])*(c2.Y[b,a]) * Yw[b,a,s],  c_i = in_i @ W_i.
// Y[b,a,(l,m)] = Pn[l,|m|,b] * trig_m(alpha_a), where Pn = Y[b,0,:] (a=0 slice,
// cos(0)=1, sqrt2 folded in) and trig_m = sin(|m|a) (m<0) / 1 (m=0) / cos(ma).
// Same for Yw -> Pw = Yw[b,0,:] (quadrature weight folded in).
//
// Per row: f_i[b,m] = sum_l c_i[l,m] Pn[l,|m|,b]           (25 FMA x2)
//          g_i[b,a] = sum_m f_i[b,m] trig[m,a]             (9 FMA x2 per a)
//          h = g1*g2;  hb[b,m] = sum_a h trig[m,a]         (9 FMA per a)
//          out[l,m] += hb[b,m] Pw[l,|m|,b]                 (25 FMA)
// Total 7796 FMA/row vs 13232 direct.
//
// Block 256 = 4 waves, 64 rows, lane = row. Wave w: c-slice in phase 1,
// betas {3w..3w+2} in phase 2, partials reduced via LDS in phase 3.

namespace {
constexpr int kD = 64, kS = 25, kRA = 11;
constexpr int kBlock = 256, kRows = 64;
constexpr int kInStride = 65;                      // odd pad: 2-way banks only
constexpr int kCStride  = 53;                      // 50 used, odd pad
constexpr int kOffIn1 = 0;
constexpr int kOffIn2 = kRows * kInStride;         // 4160
constexpr int kSmemF  = 2 * kRows * kInStride;     // 8320 floats = 33.3 KB
constexpr int kOffC   = kSmemF - kRows * kCStride; // 4928 (tail region)
constexpr int kOffPart = 0;                        // 4*64*25 = 6400 floats
}

__global__ void trig_init_kernel(float* __restrict__ trig) {
    const int t = threadIdx.x;
    if (t < kRA * 9) {
        const int a = t / 9, mi = t % 9, m = mi - 4;
        const double alpha = 2.0 * 3.14159265358979323846 * (double)a / (double)kRA;
        float v;
        if (m < 0)       v = (float)sin((double)(-m) * alpha);
        else if (m == 0) v = 1.0f;
        else             v = (float)cos((double)m * alpha);
        trig[a * 9 + mi] = v;
    }
}

__global__ __launch_bounds__(kBlock, 4) void gaunt_fused3(
    const float* __restrict__ in1, const float* __restrict__ in2,
    const float* __restrict__ W1, const float* __restrict__ W2,
    const float* __restrict__ Y,  const float* __restrict__ Yw,
    const float* __restrict__ trig,
    float* __restrict__ out)
{
    __shared__ float smem[kSmemF];
    const int tid  = threadIdx.x;
    const int lane = tid & 63;
    const int w    = __builtin_amdgcn_readfirstlane(tid >> 6);

    // ---- Phase 0: coalesced staging of this block's 64 rows ----
    const long long base = (long long)blockIdx.x * (kRows * kD);
    const float4* __restrict__ g1v = reinterpret_cast<const float4*>(in1 + base);
    const float4* __restrict__ g2v = reinterpret_cast<const float4*>(in2 + base);
    #pragma unroll
    for (int i = 0; i < (kRows * kD) / (4 * kBlock); ++i) {   // 4 iters
        const int idx = i * kBlock + tid;
        const float4 v1 = g1v[idx];
        const float4 v2 = g2v[idx];
        const int row = idx >> 4;
        const int col = (idx & 15) * 4;
        float* d1 = smem + kOffIn1 + row * kInStride + col;
        float* d2 = smem + kOffIn2 + row * kInStride + col;
        d1[0] = v1.x; d1[1] = v1.y; d1[2] = v1.z; d1[3] = v1.w;
        d2[0] = v2.x; d2[1] = v2.y; d2[2] = v2.z; d2[3] = v2.w;
    }
    __syncthreads();

    // ---- Phase 1: c slices into registers (wave 0/1: c1, wave 2/3: c2) ----
    float cp[13];
    {
        const float* __restrict__ Win = (w < 2) ? W1 : W2;      // uniform
        const int s0 = (w & 1) * 12;                             // uniform
        const float* irow = smem + ((w < 2) ? kOffIn1 : kOffIn2)
                          + lane * kInStride;
        #pragma unroll
        for (int s = 0; s < 13; ++s) cp[s] = 0.f;
        #pragma unroll 8
        for (int k = 0; k < kD; ++k) {
            const float x = irow[k];                             // ds_read
            const float* __restrict__ wr = Win + k * kS + s0;    // s_load
            #pragma unroll
            for (int s = 0; s < 13; ++s) cp[s] = fmaf(x, wr[s], cp[s]);
        }
    }
    __syncthreads();   // all input reads done before c overwrites in2 tail

    {
        const int s0    = (w & 1) * 12;
        const int cbase = (w < 2) ? 0 : kS;
        float* crow = smem + kOffC + lane * kCStride + cbase + s0;
        #pragma unroll
        for (int s = 0; s < 13; ++s) crow[s] = cp[s];
    }
    __syncthreads();

    // ---- Phase 2: separable grid transform, betas {3w, 3w+1, 3w+2} ----
    float c1r[kS], c2r[kS], outa[kS];
    {
        const float* crow = smem + kOffC + lane * kCStride;
        #pragma unroll
        for (int s = 0; s < kS; ++s) {
            c1r[s] = crow[s];
            c2r[s] = crow[kS + s];
            outa[s] = 0.f;
        }
    }
    __syncthreads();   // c reads done before partials overwrite [0,6400)

    #pragma unroll 1
    for (int j = 0; j < 3; ++j) {
        const int b = w * 3 + j;                                 // uniform
        const float* __restrict__ pn = Y  + b * (kRA * kS);      // a=0 slice
        const float* __restrict__ pw = Yw + b * (kRA * kS);

        // forward beta: f_i[m] = sum_l c_i[l,m] * Pn[l,|m|]
        float f1[9], f2[9];
        #pragma unroll
        for (int mi = 0; mi < 9; ++mi) { f1[mi] = 0.f; f2[mi] = 0.f; }
        #pragma unroll
        for (int l = 0; l <= 4; ++l) {
            #pragma unroll
            for (int m = -l; m <= l; ++m) {
                const int am = (m < 0) ? -m : m;
                const float p = pn[l * (l + 1) + am];            // s_load, CSEd
                f1[m + 4] = fmaf(c1r[l * (l + 1) + m], p, f1[m + 4]);
                f2[m + 4] = fmaf(c2r[l * (l + 1) + m], p, f2[m + 4]);
            }
        }

        // alpha transform + product + inverse alpha
        float hb[9];
        #pragma unroll
        for (int mi = 0; mi < 9; ++mi) hb[mi] = 0.f;
        #pragma unroll
        for (int a = 0; a < kRA; ++a) {
            const float* __restrict__ tr = trig + a * 9;         // s_load
            float g1 = 0.f, g2 = 0.f;
            #pragma unroll
            for (int mi = 0; mi < 9; ++mi) {
                g1 = fmaf(f1[mi], tr[mi], g1);
                g2 = fmaf(f2[mi], tr[mi], g2);
            }
            const float h = g1 * g2;
            #pragma unroll
            for (int mi = 0; mi < 9; ++mi) hb[mi] = fmaf(h, tr[mi], hb[mi]);
        }

        // inverse beta: out[l,m] += hb[m] * Pw[l,|m|]
        #pragma unroll
        for (int l = 0; l <= 4; ++l) {
            #pragma unroll
            for (int m = -l; m <= l; ++m) {
                const int am = (m < 0) ? -m : m;
                outa[l * (l + 1) + m] =
                    fmaf(hb[m + 4], pw[l * (l + 1) + am], outa[l * (l + 1) + m]);
            }
        }
    }

    // ---- Phase 3: cross-wave reduction via LDS, coalesced store ----
    {
        float* prt = smem + kOffPart + (w * kRows + lane) * kS;
        #pragma unroll
        for (int s = 0; s < kS; ++s) prt[s] = outa[s];
    }
    __syncthreads();

    {
        const float* po = smem + kOffPart;
        float* __restrict__ ob = out + (long long)blockIdx.x * (kRows * kS);
        #pragma unroll
        for (int e = tid; e < kRows * kS; e += kBlock) {
            ob[e] = po[e] + po[1600 + e] + po[3200 + e] + po[4800 + e];
        }
    }
}

extern "C" void kernel_launch(void* const* d_in, const int* in_sizes, int n_in,
                              void* d_out, int out_size, void* d_ws, size_t ws_size,
                              hipStream_t stream) {
    const float* in1 = (const float*)d_in[0];   // [N, 64]
    const float* in2 = (const float*)d_in[1];   // [N, 64]
    const float* W1  = (const float*)d_in[2];   // [64, 25]
    const float* W2  = (const float*)d_in[3];   // [64, 25]
    const float* Y   = (const float*)d_in[4];   // [12, 11, 25]
    const float* Yw  = (const float*)d_in[5];   // [12, 11, 25]
    float* out = (float*)d_out;                 // [N, 25]
    float* trig = (float*)d_ws;                 // 99 floats

    trig_init_kernel<<<1, 128, 0, stream>>>(trig);

    const int n_rows = in_sizes[0] / kD;        // 131072
    const int grid = n_rows / kRows;            // 2048
    gaunt_fused3<<<grid, kBlock, 0, stream>>>(in1, in2, W1, W2, Y, Yw, trig, out);
}

// Round 4
// 120.074 us; speedup vs baseline: 1.6261x; 1.3185x over previous
//
#include <hip/hip_runtime.h>

// GauntTensorProductFixedParity — R4: full MFMA restructure.
//
//   A1 = W1 @ Y^T  [64 x 132]   (precomputed, bf16, B-frag-swizzled)
//   A2 = W2 @ Y^T  [64 x 132]
//   B2 = Yw        [132 x 25]   (padded to [160 x 32], zero-filled)
//   G1 = in1 @ A1, G2 = in2 @ A2  (MFMA 16x16x32 bf16, K=64)
//   H  = G1 * G2   (elementwise, C-frag layout -> bf16 -> LDS)
//   out = H @ B2   (MFMA, K=160 with zero padding)
//
// Block = 256 thr = 4 waves, 128 rows. Wave w owns row-tiles {2w, 2w+1}.
// Fragment layouts (verified m89/m91): A[m=lane&15][k=(lane>>4)*8+j],
// B[k=(lane>>4)*8+j][n=lane&15], C col=lane&15, row=(lane>>4)*4+r.

typedef __bf16 bf16x8 __attribute__((ext_vector_type(8)));
typedef float f32x4 __attribute__((ext_vector_type(4)));

namespace {
constexpr int kD = 64, kS = 25, kP = 132;
constexpr int kBlock = 256, kM = 128;          // rows per block
constexpr int kInStride = 72;                  // bf16 units; 144B rows, 16B-aligned
constexpr int kHStride = 168;                  // bf16 units; 336B rows, 16B-aligned
constexpr int kOffIn2 = kM * kInStride;        // 9216
constexpr int kSmemU = kM * kHStride;          // 21504 ushorts = 43008 B (H overlays inputs)
// d_ws layout (ushort units): A1sw [9*2*64*8=9216], A2sw [9216], B2sw [2*5*64*8=5120]
constexpr int kWsA2 = 9216, kWsB2 = 18432;
}

__device__ __forceinline__ unsigned short f2bf(float f) {
    unsigned int u = __builtin_bit_cast(unsigned int, f);
    u += 0x7FFFu + ((u >> 16) & 1u);           // RNE
    return (unsigned short)(u >> 16);
}

__device__ __forceinline__ bf16x8 ld_frag_g(const unsigned short* p) {
    int4 v = *reinterpret_cast<const int4*>(p);
    return __builtin_bit_cast(bf16x8, v);
}

// ---- Precompute A1sw/A2sw/B2sw into d_ws ----
__global__ void precompute_kernel(const float* __restrict__ W1,
                                  const float* __restrict__ W2,
                                  const float* __restrict__ Y,
                                  const float* __restrict__ Yw,
                                  unsigned short* __restrict__ ws) {
    const int t0 = blockIdx.x * blockDim.x + threadIdx.x;
    const int stride = gridDim.x * blockDim.x;
    // A1/A2: e -> [ntile(9)][kstep(2)][lane(64)][j(8)], value A[k][n]
    for (int e = t0; e < 9216; e += stride) {
        const int j = e & 7, lane = (e >> 3) & 63, ks = (e >> 9) & 1, nt = e >> 10;
        const int k = ks * 32 + (lane >> 4) * 8 + j;     // d index, 0..63
        const int n = nt * 16 + (lane & 15);             // p index, 0..143
        float v1 = 0.f, v2 = 0.f;
        if (n < kP) {
            const float* yr = Y + n * kS;
            const float* w1 = W1 + k * kS;
            const float* w2 = W2 + k * kS;
            #pragma unroll
            for (int s = 0; s < kS; ++s) {
                v1 = fmaf(w1[s], yr[s], v1);
                v2 = fmaf(w2[s], yr[s], v2);
            }
        }
        ws[e]         = f2bf(v1);
        ws[kWsA2 + e] = f2bf(v2);
    }
    // B2: e -> [ntile(2)][kstep(5)][lane(64)][j(8)], value Yw[k][n]
    for (int e = t0; e < 5120; e += stride) {
        const int j = e & 7, lane = (e >> 3) & 63, r = e >> 9;
        const int ks = r % 5, nt = r / 5;
        const int k = ks * 32 + (lane >> 4) * 8 + j;     // p index, 0..159
        const int n = nt * 16 + (lane & 15);             // s index, 0..31
        ws[kWsB2 + e] = (k < kP && n < kS) ? f2bf(Yw[k * kS + n]) : (unsigned short)0;
    }
}

__global__ __launch_bounds__(kBlock, 3) void gaunt_mfma(
    const float* __restrict__ in1, const float* __restrict__ in2,
    const unsigned short* __restrict__ ws, float* __restrict__ out)
{
    __shared__ unsigned short smem[kSmemU];
    const int tid  = threadIdx.x;
    const int lane = tid & 63;
    const int w    = __builtin_amdgcn_readfirstlane(tid >> 6);
    const int lo16 = lane & 15, quad = lane >> 4;

    // ---- Phase 0: stage inputs [128x64] fp32 -> bf16 LDS (stride 72) ----
    const long long base = (long long)blockIdx.x * (kM * kD);
    const float4* __restrict__ g1v = reinterpret_cast<const float4*>(in1 + base);
    const float4* __restrict__ g2v = reinterpret_cast<const float4*>(in2 + base);
    #pragma unroll
    for (int i = 0; i < (kM * kD) / (4 * kBlock); ++i) {   // 8 iters
        const int idx = i * kBlock + tid;                  // float4 idx 0..2047
        const int row = idx >> 4, c4 = (idx & 15) * 4;
        const float4 v1 = g1v[idx];
        const float4 v2 = g2v[idx];
        ushort4 p1, p2;
        p1.x = f2bf(v1.x); p1.y = f2bf(v1.y); p1.z = f2bf(v1.z); p1.w = f2bf(v1.w);
        p2.x = f2bf(v2.x); p2.y = f2bf(v2.y); p2.z = f2bf(v2.z); p2.w = f2bf(v2.w);
        *reinterpret_cast<ushort4*>(&smem[row * kInStride + c4])          = p1;
        *reinterpret_cast<ushort4*>(&smem[kOffIn2 + row * kInStride + c4]) = p2;
    }
    __syncthreads();

    // ---- a-fragments for GEMM1 (rows of in1/in2), held across n-loop ----
    bf16x8 a1f[2][2], a2f[2][2];
    #pragma unroll
    for (int rt = 0; rt < 2; ++rt) {
        const int row = (2 * w + rt) * 16 + lo16;
        const int kbase = row * kInStride + quad * 8;
        #pragma unroll
        for (int ks = 0; ks < 2; ++ks) {
            a1f[rt][ks] = ld_frag_g(&smem[kbase + ks * 32]);
            a2f[rt][ks] = ld_frag_g(&smem[kOffIn2 + kbase + ks * 32]);
        }
    }
    __syncthreads();   // all input reads done; H may now overwrite the region

    // ---- zero H padding cols [144,168) (read by GEMM2 kstep 4) ----
    {
        const int r = tid >> 1, half = tid & 1;
        unsigned int* p =
            reinterpret_cast<unsigned int*>(&smem[r * kHStride + 144 + half * 12]);
        p[0] = 0u; p[1] = 0u; p[2] = 0u; p[3] = 0u; p[4] = 0u; p[5] = 0u;
    }

    // ---- GEMM1 + product: 9 col-tiles; b-frags double-buffered ----
    const unsigned short* wsA1 = ws;
    const unsigned short* wsA2 = ws + kWsA2;
    bf16x8 b1c[2], b2c[2], b1n[2], b2n[2];
    #pragma unroll
    for (int ks = 0; ks < 2; ++ks) {
        b1c[ks] = ld_frag_g(&wsA1[(0 * 2 + ks) * 512 + lane * 8]);
        b2c[ks] = ld_frag_g(&wsA2[(0 * 2 + ks) * 512 + lane * 8]);
    }
    #pragma unroll 1
    for (int nt = 0; nt < 9; ++nt) {
        if (nt < 8) {
            #pragma unroll
            for (int ks = 0; ks < 2; ++ks) {
                b1n[ks] = ld_frag_g(&wsA1[((nt + 1) * 2 + ks) * 512 + lane * 8]);
                b2n[ks] = ld_frag_g(&wsA2[((nt + 1) * 2 + ks) * 512 + lane * 8]);
            }
        }
        f32x4 g1[2], g2[2];
        #pragma unroll
        for (int rt = 0; rt < 2; ++rt) {
            g1[rt] = (f32x4){0.f, 0.f, 0.f, 0.f};
            g2[rt] = (f32x4){0.f, 0.f, 0.f, 0.f};
            #pragma unroll
            for (int ks = 0; ks < 2; ++ks) {
                g1[rt] = __builtin_amdgcn_mfma_f32_16x16x32_bf16(
                    a1f[rt][ks], b1c[ks], g1[rt], 0, 0, 0);
                g2[rt] = __builtin_amdgcn_mfma_f32_16x16x32_bf16(
                    a2f[rt][ks], b2c[ks], g2[rt], 0, 0, 0);
            }
        }
        // H = G1*G2 -> bf16 -> LDS (C-frag: col=lo16, row=quad*4+i)
        const int hcol = nt * 16 + lo16;
        #pragma unroll
        for (int rt = 0; rt < 2; ++rt) {
            #pragma unroll
            for (int i = 0; i < 4; ++i) {
                const int row = (2 * w + rt) * 16 + quad * 4 + i;
                smem[row * kHStride + hcol] = f2bf(g1[rt][i] * g2[rt][i]);
            }
        }
        #pragma unroll
        for (int ks = 0; ks < 2; ++ks) { b1c[ks] = b1n[ks]; b2c[ks] = b2n[ks]; }
    }
    __syncthreads();

    // ---- GEMM2: out[128x25] = H[128x160] @ B2 ----
    const unsigned short* wsB2 = ws + kWsB2;
    f32x4 o[2][2];
    #pragma unroll
    for (int rt = 0; rt < 2; ++rt)
        #pragma unroll
        for (int nt = 0; nt < 2; ++nt)
            o[rt][nt] = (f32x4){0.f, 0.f, 0.f, 0.f};

    bf16x8 bbc[2], bbn[2];
    #pragma unroll
    for (int nt = 0; nt < 2; ++nt)
        bbc[nt] = ld_frag_g(&wsB2[(nt * 5 + 0) * 512 + lane * 8]);

    #pragma unroll 1
    for (int ks = 0; ks < 5; ++ks) {
        if (ks < 4) {
            #pragma unroll
            for (int nt = 0; nt < 2; ++nt)
                bbn[nt] = ld_frag_g(&wsB2[(nt * 5 + ks + 1) * 512 + lane * 8]);
        }
        bf16x8 hf[2];
        #pragma unroll
        for (int rt = 0; rt < 2; ++rt) {
            const int row = (2 * w + rt) * 16 + lo16;
            hf[rt] = ld_frag_g(&smem[row * kHStride + ks * 32 + quad * 8]);
        }
        #pragma unroll
        for (int rt = 0; rt < 2; ++rt)
            #pragma unroll
            for (int nt = 0; nt < 2; ++nt)
                o[rt][nt] = __builtin_amdgcn_mfma_f32_16x16x32_bf16(
                    hf[rt], bbc[nt], o[rt][nt], 0, 0, 0);
        bbc[0] = bbn[0]; bbc[1] = bbn[1];
    }

    // ---- Epilogue: direct stores (cols >= 25 dropped) ----
    const long long ob = (long long)blockIdx.x * (kM * kS);
    #pragma unroll
    for (int rt = 0; rt < 2; ++rt) {
        #pragma unroll
        for (int nt = 0; nt < 2; ++nt) {
            const int col = nt * 16 + lo16;
            if (col < kS) {
                #pragma unroll
                for (int i = 0; i < 4; ++i) {
                    const int row = (2 * w + rt) * 16 + quad * 4 + i;
                    out[ob + row * kS + col] = o[rt][nt][i];
                }
            }
        }
    }
}

extern "C" void kernel_launch(void* const* d_in, const int* in_sizes, int n_in,
                              void* d_out, int out_size, void* d_ws, size_t ws_size,
                              hipStream_t stream) {
    const float* in1 = (const float*)d_in[0];   // [N, 64]
    const float* in2 = (const float*)d_in[1];   // [N, 64]
    const float* W1  = (const float*)d_in[2];   // [64, 25]
    const float* W2  = (const float*)d_in[3];   // [64, 25]
    const float* Y   = (const float*)d_in[4];   // [132, 25]
    const float* Yw  = (const float*)d_in[5];   // [132, 25]
    float* out = (float*)d_out;                 // [N, 25]
    unsigned short* ws = (unsigned short*)d_ws; // 23552 ushorts = 47 KB

    precompute_kernel<<<8, 256, 0, stream>>>(W1, W2, Y, Yw, ws);

    const int n_rows = in_sizes[0] / kD;        // 131072
    const int grid = n_rows / kM;               // 1024
    gaunt_mfma<<<grid, kBlock, 0, stream>>>(in1, in2, ws, out);
}

// Round 5
// 117.966 us; speedup vs baseline: 1.6552x; 1.0179x over previous
//
#include <hip/hip_runtime.h>

// GauntTensorProductFixedParity — R5: barrier-free MFMA, direct global A-frags.
//
//   A1 = W1 @ Y^T [64x132], A2 = W2 @ Y^T (bf16, B-frag-swizzled in d_ws)
//   B2 = Yw [132x25] padded to [160x32], zero-filled, B-frag-swizzled
//   G1 = in1 @ A1, G2 = in2 @ A2   (mfma 16x16x32 bf16, K=64, direct A loads)
//   H  = G1 * G2  -> bf16 -> LDS (C-frag -> A-frag transpose, wave-private)
//   out = H @ B2                   (K=160 incl. zero pad)
//
// Block 256 = 4 waves = 128 rows; wave w owns row-tiles {2w,2w+1} end-to-end:
// no H sharing across waves -> NO __syncthreads anywhere.
// A-frag (row=lane&15, k=quad*8+j) == 16B-contiguous global load per lane.

typedef __bf16 bf16x8 __attribute__((ext_vector_type(8)));
typedef float f32x4 __attribute__((ext_vector_type(4)));

namespace {
constexpr int kD = 64, kS = 25, kP = 132;
constexpr int kBlock = 256, kM = 128;          // rows per block
constexpr int kHStride = 168;                  // ushorts; 336B rows: 16B-aligned,
                                               // quad-row step = 336dw %32 = 16 (2-way)
constexpr int kSmemU = kM * kHStride;          // 21504 ushorts = 43008 B
constexpr int kWsA2 = 9216, kWsB2 = 18432;     // ushort offsets in d_ws
}

__device__ __forceinline__ unsigned short f2bf(float f) {
    unsigned int u = __builtin_bit_cast(unsigned int, f);
    u += 0x7FFFu + ((u >> 16) & 1u);           // RNE
    return (unsigned short)(u >> 16);
}

__device__ __forceinline__ bf16x8 ld_frag_g(const unsigned short* p) {
    int4 v = *reinterpret_cast<const int4*>(p);
    return __builtin_bit_cast(bf16x8, v);
}

__device__ __forceinline__ bf16x8 cvt8(f32x4 u, f32x4 v) {
    bf16x8 r;
    r[0] = (__bf16)u[0]; r[1] = (__bf16)u[1]; r[2] = (__bf16)u[2]; r[3] = (__bf16)u[3];
    r[4] = (__bf16)v[0]; r[5] = (__bf16)v[1]; r[6] = (__bf16)v[2]; r[7] = (__bf16)v[3];
    return r;
}

// ---- Precompute A1sw/A2sw/B2sw into d_ws (runs every launch) ----
__global__ void precompute_kernel(const float* __restrict__ W1,
                                  const float* __restrict__ W2,
                                  const float* __restrict__ Y,
                                  const float* __restrict__ Yw,
                                  unsigned short* __restrict__ ws) {
    const int t0 = blockIdx.x * blockDim.x + threadIdx.x;
    const int stride = gridDim.x * blockDim.x;
    // A1/A2: e -> [ntile(9)][kstep(2)][lane(64)][j(8)], value A[k][n]
    for (int e = t0; e < 9216; e += stride) {
        const int j = e & 7, lane = (e >> 3) & 63, ks = (e >> 9) & 1, nt = e >> 10;
        const int k = ks * 32 + (lane >> 4) * 8 + j;     // d index, 0..63
        const int n = nt * 16 + (lane & 15);             // p index, 0..143
        float v1 = 0.f, v2 = 0.f;
        if (n < kP) {
            const float* yr = Y + n * kS;
            const float* w1 = W1 + k * kS;
            const float* w2 = W2 + k * kS;
            #pragma unroll
            for (int s = 0; s < kS; ++s) {
                v1 = fmaf(w1[s], yr[s], v1);
                v2 = fmaf(w2[s], yr[s], v2);
            }
        }
        ws[e]         = f2bf(v1);
        ws[kWsA2 + e] = f2bf(v2);
    }
    // B2: e -> [ntile(2)][kstep(5)][lane(64)][j(8)], value Yw[k][n]
    for (int e = t0; e < 5120; e += stride) {
        const int j = e & 7, lane = (e >> 3) & 63, r = e >> 9;
        const int ks = r % 5, nt = r / 5;
        const int k = ks * 32 + (lane >> 4) * 8 + j;     // p index, 0..159
        const int n = nt * 16 + (lane & 15);             // s index, 0..31
        ws[kWsB2 + e] = (k < kP && n < kS) ? f2bf(Yw[k * kS + n]) : (unsigned short)0;
    }
}

__global__ __launch_bounds__(kBlock, 3) void gaunt_mfma5(
    const float* __restrict__ in1, const float* __restrict__ in2,
    const unsigned short* __restrict__ ws, float* __restrict__ out)
{
    __shared__ unsigned short smem[kSmemU];
    const int tid  = threadIdx.x;
    const int lane = tid & 63;
    const int w    = __builtin_amdgcn_readfirstlane(tid >> 6);
    const int lo16 = lane & 15, quad = lane >> 4;

    // ---- zero H pad cols [144,160). tid covers row=tid/2 in [32w,32w+32):
    //      exactly this wave's own rows -> wave-ordered, no barrier. ----
    {
        const int r = tid >> 1, c = 144 + (tid & 1) * 8;
        *reinterpret_cast<int4*>(&smem[r * kHStride + c]) = (int4){0, 0, 0, 0};
    }

    // ---- A-fragments straight from global (16B contiguous per lane) ----
    const long long base = (long long)blockIdx.x * (kM * kD);
    bf16x8 a1f[2][2], a2f[2][2];
    #pragma unroll
    for (int rt = 0; rt < 2; ++rt) {
        const int row = (2 * w + rt) * 16 + lo16;
        const float* p1 = in1 + base + row * kD + quad * 8;
        const float* p2 = in2 + base + row * kD + quad * 8;
        #pragma unroll
        for (int ks = 0; ks < 2; ++ks) {
            const f32x4 u1 = *reinterpret_cast<const f32x4*>(p1 + ks * 32);
            const f32x4 v1 = *reinterpret_cast<const f32x4*>(p1 + ks * 32 + 4);
            const f32x4 u2 = *reinterpret_cast<const f32x4*>(p2 + ks * 32);
            const f32x4 v2 = *reinterpret_cast<const f32x4*>(p2 + ks * 32 + 4);
            a1f[rt][ks] = cvt8(u1, v1);
            a2f[rt][ks] = cvt8(u2, v2);
        }
    }

    // ---- GEMM1 + product -> H in LDS (wave-private rows) ----
    const unsigned short* wsA1 = ws;
    const unsigned short* wsA2 = ws + kWsA2;
    bf16x8 b1c[2], b2c[2], b1n[2], b2n[2];
    #pragma unroll
    for (int ks = 0; ks < 2; ++ks) {
        b1c[ks] = ld_frag_g(&wsA1[ks * 512 + lane * 8]);
        b2c[ks] = ld_frag_g(&wsA2[ks * 512 + lane * 8]);
    }
    #pragma unroll 1
    for (int nt = 0; nt < 9; ++nt) {
        if (nt < 8) {
            #pragma unroll
            for (int ks = 0; ks < 2; ++ks) {
                b1n[ks] = ld_frag_g(&wsA1[((nt + 1) * 2 + ks) * 512 + lane * 8]);
                b2n[ks] = ld_frag_g(&wsA2[((nt + 1) * 2 + ks) * 512 + lane * 8]);
            }
        }
        #pragma unroll
        for (int rt = 0; rt < 2; ++rt) {
            f32x4 g1 = (f32x4){0.f, 0.f, 0.f, 0.f};
            f32x4 g2 = (f32x4){0.f, 0.f, 0.f, 0.f};
            #pragma unroll
            for (int ks = 0; ks < 2; ++ks) {
                g1 = __builtin_amdgcn_mfma_f32_16x16x32_bf16(a1f[rt][ks], b1c[ks], g1, 0, 0, 0);
                g2 = __builtin_amdgcn_mfma_f32_16x16x32_bf16(a2f[rt][ks], b2c[ks], g2, 0, 0, 0);
            }
            const int hcol = nt * 16 + lo16;
            #pragma unroll
            for (int i = 0; i < 4; ++i) {
                const int row = (2 * w + rt) * 16 + quad * 4 + i;
                smem[row * kHStride + hcol] =
                    __builtin_bit_cast(unsigned short, (__bf16)(g1[i] * g2[i]));
            }
        }
        #pragma unroll
        for (int ks = 0; ks < 2; ++ks) { b1c[ks] = b1n[ks]; b2c[ks] = b2n[ks]; }
    }

    // ---- GEMM2: out[128x25] = H[128x160] @ B2 (same-wave H: lgkmcnt orders) ----
    const unsigned short* wsB2 = ws + kWsB2;
    f32x4 o[2][2];
    #pragma unroll
    for (int rt = 0; rt < 2; ++rt)
        #pragma unroll
        for (int nt = 0; nt < 2; ++nt)
            o[rt][nt] = (f32x4){0.f, 0.f, 0.f, 0.f};

    bf16x8 bbc[2], bbn[2];
    #pragma unroll
    for (int nt = 0; nt < 2; ++nt)
        bbc[nt] = ld_frag_g(&wsB2[(nt * 5) * 512 + lane * 8]);

    #pragma unroll 1
    for (int ks = 0; ks < 5; ++ks) {
        if (ks < 4) {
            #pragma unroll
            for (int nt = 0; nt < 2; ++nt)
                bbn[nt] = ld_frag_g(&wsB2[(nt * 5 + ks + 1) * 512 + lane * 8]);
        }
        bf16x8 hf[2];
        #pragma unroll
        for (int rt = 0; rt < 2; ++rt) {
            const int row = (2 * w + rt) * 16 + lo16;
            const int4 hv = *reinterpret_cast<const int4*>(
                &smem[row * kHStride + ks * 32 + quad * 8]);
            hf[rt] = __builtin_bit_cast(bf16x8, hv);
        }
        #pragma unroll
        for (int rt = 0; rt < 2; ++rt)
            #pragma unroll
            for (int nt = 0; nt < 2; ++nt)
                o[rt][nt] = __builtin_amdgcn_mfma_f32_16x16x32_bf16(
                    hf[rt], bbc[nt], o[rt][nt], 0, 0, 0);
        bbc[0] = bbn[0]; bbc[1] = bbn[1];
    }

    // ---- Epilogue: direct stores (64B-contiguous per quad-row; col>=25 off) ----
    const long long ob = (long long)blockIdx.x * (kM * kS);
    #pragma unroll
    for (int rt = 0; rt < 2; ++rt) {
        #pragma unroll
        for (int nt = 0; nt < 2; ++nt) {
            const int col = nt * 16 + lo16;
            if (col < kS) {
                #pragma unroll
                for (int i = 0; i < 4; ++i) {
                    const int row = (2 * w + rt) * 16 + quad * 4 + i;
                    out[ob + row * kS + col] = o[rt][nt][i];
                }
            }
        }
    }
}

extern "C" void kernel_launch(void* const* d_in, const int* in_sizes, int n_in,
                              void* d_out, int out_size, void* d_ws, size_t ws_size,
                              hipStream_t stream) {
    const float* in1 = (const float*)d_in[0];   // [N, 64]
    const float* in2 = (const float*)d_in[1];   // [N, 64]
    const float* W1  = (const float*)d_in[2];   // [64, 25]
    const float* W2  = (const float*)d_in[3];   // [64, 25]
    const float* Y   = (const float*)d_in[4];   // [132, 25]
    const float* Yw  = (const float*)d_in[5];   // [132, 25]
    float* out = (float*)d_out;                 // [N, 25]
    unsigned short* ws = (unsigned short*)d_ws; // 23552 ushorts used

    precompute_kernel<<<8, 256, 0, stream>>>(W1, W2, Y, Yw, ws);

    const int n_rows = in_sizes[0] / kD;        // 131072
    const int grid = n_rows / kM;               // 1024
    gaunt_mfma5<<<grid, kBlock, 0, stream>>>(in1, in2, ws, out);
}

// Round 6
// 116.999 us; speedup vs baseline: 1.6689x; 1.0083x over previous
//
#include <hip/hip_runtime.h>

// GauntTensorProductFixedParity — R6: register-resident pipeline, zero LDS.
//
//   A1t = (W1 @ Y^T)^T  [132x64 -> padded 144x64]  (fp16, A-frag-swizzled)
//   A2t = (W2 @ Y^T)^T
//   Ywt = Yw^T          [25x132 -> padded 32x144]  (fp16, A-frag for K=16)
//
//   GEMM1 (16x16x32 f16): G^T = A1t · in^T  -> C-layout: lane holds
//          p = quad*4+i, row = lo16  == B-operand layout of K=16 MFMA.
//   H = G1^T ⊙ G2^T (elementwise in registers, f32->f16)
//   GEMM2 (16x16x16 f16): out^T = Ywt · H    -> C-layout: lane holds
//          s = quad*4+i, row = lo16 -> 16B-contiguous per-lane stores.
//
// No LDS, no barriers, everything register-resident. Block 256 = 4 waves,
// wave w owns row-tiles {2w, 2w+1} (32 rows), 128 rows/block.

typedef _Float16 f16x8 __attribute__((ext_vector_type(8)));
typedef _Float16 f16x4 __attribute__((ext_vector_type(4)));
typedef float f32x4 __attribute__((ext_vector_type(4)));
typedef float f32x4u __attribute__((ext_vector_type(4), aligned(4)));

namespace {
constexpr int kD = 64, kS = 25, kP = 132;
constexpr int kBlock = 256, kM = 128;            // rows per block
// d_ws layout in _Float16 units:
//   A1t frags [pt(9)][ks(2)][lane(64)][j(8)] = 9216
//   A2t frags                                 = 9216
//   Ywt frags [st(2)][pt(9)][lane(64)][i(4)]  = 4608
constexpr int kWsA2 = 9216, kWsYw = 18432;
}

// ---- Precompute swizzled fp16 operands into d_ws (every launch) ----
__global__ void precompute_kernel(const float* __restrict__ W1,
                                  const float* __restrict__ W2,
                                  const float* __restrict__ Y,
                                  const float* __restrict__ Yw,
                                  _Float16* __restrict__ ws) {
    const int t0 = blockIdx.x * blockDim.x + threadIdx.x;
    const int stride = gridDim.x * blockDim.x;
    // A1t/A2t: value A1t[p][d] = sum_s W[d][s] Y[p][s];  p from lane&15+tile,
    // d from ks*32 + quad*8 + j.  p >= 132 -> 0.
    for (int e = t0; e < 9216; e += stride) {
        const int j = e & 7, lane = (e >> 3) & 63, ks = (e >> 9) & 1, pt = e >> 10;
        const int d = ks * 32 + (lane >> 4) * 8 + j;     // 0..63
        const int p = pt * 16 + (lane & 15);             // 0..143
        float v1 = 0.f, v2 = 0.f;
        if (p < kP) {
            const float* yr = Y + p * kS;
            const float* w1 = W1 + d * kS;
            const float* w2 = W2 + d * kS;
            #pragma unroll
            for (int s = 0; s < kS; ++s) {
                v1 = fmaf(w1[s], yr[s], v1);
                v2 = fmaf(w2[s], yr[s], v2);
            }
        }
        ws[e]         = (_Float16)v1;
        ws[kWsA2 + e] = (_Float16)v2;
    }
    // Ywt: A-frag (K=16) value Ywt[s][p] = Yw[p][s]; s = st*16 + lane&15,
    // p = pt*16 + quad*4 + i.  Zero outside [25) x [132).
    for (int e = t0; e < 4608; e += stride) {
        const int i = e & 3, lane = (e >> 2) & 63, r = e >> 8;  // r 0..17
        const int pt = r % 9, st = r / 9;
        const int p = pt * 16 + ((lane >> 4) & 3) * 4 + i;      // 0..143
        const int s = st * 16 + (lane & 15);                    // 0..31
        ws[kWsYw + e] = (s < kS && p < kP) ? (_Float16)Yw[p * kS + s]
                                           : (_Float16)0.f;
    }
}

__device__ __forceinline__ f16x8 ld8(const _Float16* p) {
    return *reinterpret_cast<const f16x8*>(p);
}
__device__ __forceinline__ f16x4 ld4(const _Float16* p) {
    return *reinterpret_cast<const f16x4*>(p);
}
__device__ __forceinline__ f16x8 cvt8h(f32x4 u, f32x4 v) {
    f16x8 r;
    r[0] = (_Float16)u[0]; r[1] = (_Float16)u[1];
    r[2] = (_Float16)u[2]; r[3] = (_Float16)u[3];
    r[4] = (_Float16)v[0]; r[5] = (_Float16)v[1];
    r[6] = (_Float16)v[2]; r[7] = (_Float16)v[3];
    return r;
}

__global__ __launch_bounds__(kBlock, 4) void gaunt_mfma6(
    const float* __restrict__ in1, const float* __restrict__ in2,
    const _Float16* __restrict__ ws, float* __restrict__ out)
{
    const int tid  = threadIdx.x;
    const int lane = tid & 63;
    const int w    = __builtin_amdgcn_readfirstlane(tid >> 6);
    const int lo16 = lane & 15, quad = lane >> 4;

    // ---- input B-frags (in^T): lane n=row=lo16, k=d=ks*32+quad*8+j ----
    const long long base = (long long)blockIdx.x * (kM * kD);
    f16x8 b1[2][2], b2[2][2];
    #pragma unroll
    for (int rt = 0; rt < 2; ++rt) {
        const int row = (2 * w + rt) * 16 + lo16;
        const float* p1 = in1 + base + row * kD + quad * 8;
        const float* p2 = in2 + base + row * kD + quad * 8;
        #pragma unroll
        for (int ks = 0; ks < 2; ++ks) {
            const f32x4 u1 = *reinterpret_cast<const f32x4*>(p1 + ks * 32);
            const f32x4 v1 = *reinterpret_cast<const f32x4*>(p1 + ks * 32 + 4);
            const f32x4 u2 = *reinterpret_cast<const f32x4*>(p2 + ks * 32);
            const f32x4 v2 = *reinterpret_cast<const f32x4*>(p2 + ks * 32 + 4);
            b1[rt][ks] = cvt8h(u1, v1);
            b2[rt][ks] = cvt8h(u2, v2);
        }
    }

    const _Float16* wsA1 = ws;
    const _Float16* wsA2 = ws + kWsA2;
    const _Float16* wsYw = ws + kWsYw;

    f32x4 oacc[2][2];
    #pragma unroll
    for (int rt = 0; rt < 2; ++rt)
        #pragma unroll
        for (int st = 0; st < 2; ++st)
            oacc[rt][st] = (f32x4){0.f, 0.f, 0.f, 0.f};

    // ---- double-buffered operand frags over 9 p-tiles ----
    f16x8 a1c[2], a2c[2], a1n[2], a2n[2];
    f16x4 ywc[2], ywn[2];
    #pragma unroll
    for (int ks = 0; ks < 2; ++ks) {
        a1c[ks] = ld8(&wsA1[ks * 512 + lane * 8]);
        a2c[ks] = ld8(&wsA2[ks * 512 + lane * 8]);
    }
    #pragma unroll
    for (int st = 0; st < 2; ++st)
        ywc[st] = ld4(&wsYw[(st * 9) * 256 + lane * 4]);

    #pragma unroll 1
    for (int pt = 0; pt < 9; ++pt) {
        if (pt < 8) {
            #pragma unroll
            for (int ks = 0; ks < 2; ++ks) {
                a1n[ks] = ld8(&wsA1[((pt + 1) * 2 + ks) * 512 + lane * 8]);
                a2n[ks] = ld8(&wsA2[((pt + 1) * 2 + ks) * 512 + lane * 8]);
            }
            #pragma unroll
            for (int st = 0; st < 2; ++st)
                ywn[st] = ld4(&wsYw[(st * 9 + pt + 1) * 256 + lane * 4]);
        }
        #pragma unroll
        for (int rt = 0; rt < 2; ++rt) {
            f32x4 g1 = (f32x4){0.f, 0.f, 0.f, 0.f};
            f32x4 g2 = (f32x4){0.f, 0.f, 0.f, 0.f};
            #pragma unroll
            for (int ks = 0; ks < 2; ++ks) {
                g1 = __builtin_amdgcn_mfma_f32_16x16x32_f16(a1c[ks], b1[rt][ks], g1, 0, 0, 0);
                g2 = __builtin_amdgcn_mfma_f32_16x16x32_f16(a2c[ks], b2[rt][ks], g2, 0, 0, 0);
            }
            f16x4 h;
            h[0] = (_Float16)(g1[0] * g2[0]);
            h[1] = (_Float16)(g1[1] * g2[1]);
            h[2] = (_Float16)(g1[2] * g2[2]);
            h[3] = (_Float16)(g1[3] * g2[3]);
            #pragma unroll
            for (int st = 0; st < 2; ++st)
                oacc[rt][st] = __builtin_amdgcn_mfma_f32_16x16x16f16(
                    ywc[st], h, oacc[rt][st], 0, 0, 0);
        }
        #pragma unroll
        for (int ks = 0; ks < 2; ++ks) { a1c[ks] = a1n[ks]; a2c[ks] = a2n[ks]; }
        ywc[0] = ywn[0]; ywc[1] = ywn[1];
    }

    // ---- stores: out^T C-layout -> per-lane 16B-contiguous runs ----
    const long long ob = (long long)blockIdx.x * (kM * kS);
    #pragma unroll
    for (int rt = 0; rt < 2; ++rt) {
        const int row = (2 * w + rt) * 16 + lo16;
        float* rp = out + ob + (long long)row * kS;
        // st=0: s = quad*4 + i, 0..15 all valid
        *reinterpret_cast<f32x4u*>(rp + quad * 4) = oacc[rt][0];
        // st=1: s = 16 + quad*4 + i, valid while < 25
        if (quad < 2) {
            *reinterpret_cast<f32x4u*>(rp + 16 + quad * 4) = oacc[rt][1];
        } else if (quad == 2) {
            rp[24] = oacc[rt][1][0];
        }
    }
}

extern "C" void kernel_launch(void* const* d_in, const int* in_sizes, int n_in,
                              void* d_out, int out_size, void* d_ws, size_t ws_size,
                              hipStream_t stream) {
    const float* in1 = (const float*)d_in[0];   // [N, 64]
    const float* in2 = (const float*)d_in[1];   // [N, 64]
    const float* W1  = (const float*)d_in[2];   // [64, 25]
    const float* W2  = (const float*)d_in[3];   // [64, 25]
    const float* Y   = (const float*)d_in[4];   // [132, 25]
    const float* Yw  = (const float*)d_in[5];   // [132, 25]
    float* out = (float*)d_out;                 // [N, 25]
    _Float16* ws = (_Float16*)d_ws;             // 23040 halfs used

    precompute_kernel<<<16, 256, 0, stream>>>(W1, W2, Y, Yw, ws);

    const int n_rows = in_sizes[0] / kD;        // 131072
    const int grid = n_rows / kM;               // 1024
    gaunt_mfma6<<<grid, kBlock, 0, stream>>>(in1, in2, ws, out);
}